// Round 8
// baseline (1350.502 us; speedup 1.0000x reference)
//
#include <hip/hip_runtime.h>

#define K_CB   8192
#define D_DIM  256
#define N_ROWS 32768
#define Q_ELEMS (N_ROWS * D_DIM)

#define SW_F   520192.0f      // int8 scale for -2w: 127*4096; |-2w|*SW <= 127 exactly
#define M_FLAG 3.4e-4f        // np-window 6.1e-5 + i8 quant 8sigma*sqrt2 (2.5e-4) + pack 1.5e-5
#define M_CAND 3.4e-4f
#define CAP    16

typedef int   i32x4  __attribute__((ext_vector_type(4)));
typedef int   i32x16 __attribute__((ext_vector_type(16)));

// async 16B global->LDS DMA: LDS dest is WAVE-UNIFORM base; HW adds lane*16.
#define ASYNC_COPY16(gp, lp)                                              \
    __builtin_amdgcn_global_load_lds(                                     \
        (const __attribute__((address_space(1))) unsigned int*)(gp),      \
        (__attribute__((address_space(3))) unsigned int*)(lp), 16, 0, 0)

// ws layout (bytes):
//   0        Wsq   [8192 f32]     (np-exact w_sq)
//   32768    Xsq   [32768 f32]
//   163840   Sx    [32768 f32]    127/rowmax
//   294912   invS  [32768 f32]    1/(Sx*SW)
//   425984   accum f32 | 425988 hard_count u32 | 425992 done u32  (prep zeroes)
//   426000   hard  [32768 i32]
//   557072   candcnt [32768 i32]  (-1 = hard, 0 = decided, >0 = rescore list len)
//   688144   cands [32768*16 i32] (hard rows: first 8 bytes = u64 atomicMin cell)
//   2785296  Wq    [8192*256 i8] = int8(rint(-2w*SW)), PRE-SWIZZLED tile layout:
//            byte(k,d): tile=k>>7, c=k&127, sl=d>>4 ->
//            tile*32768 + c*256 + ((sl ^ (c&15))*16) + (d&15)

__device__ inline unsigned q4(float4 f, float s) {   // 4x rint(f*s) -> packed bytes
    int a = __float2int_rn(f.x * s), b = __float2int_rn(f.y * s);
    int c = __float2int_rn(f.z * s), d = __float2int_rn(f.w * s);
    return (a & 255) | ((b & 255) << 8) | ((c & 255) << 16) | ((d & 255) << 24);
}

// prep: Wsq + swizzled int8 Wq (blocks 0..2047), Xsq/Sx/invS (blocks 2048..10239), zero counters
__global__ void prep_kernel(const float* __restrict__ w, const float* __restrict__ x,
                            float* __restrict__ wsq, float* __restrict__ xsq,
                            float* __restrict__ sx, float* __restrict__ invs,
                            char* __restrict__ wq, unsigned* __restrict__ counters) {
    if (blockIdx.x == 0 && threadIdx.x < 3) counters[threadIdx.x] = 0;
    int wave = threadIdx.x >> 6, lane = threadIdx.x & 63;
    if (blockIdx.x < 2048) {
        int k = blockIdx.x * 4 + wave;
        float4 v = reinterpret_cast<const float4*>(w)[(size_t)k * 64 + lane];
        unsigned qq = q4(v, -2.0f * SW_F);
        int c = k & 127, tile = k >> 7, sl = lane >> 2;
        size_t dst = (size_t)tile * 32768 + (size_t)c * 256
                   + (size_t)((sl ^ (c & 15)) << 4) + (lane & 3) * 4;
        *reinterpret_cast<unsigned*>(wq + dst) = qq;
        double sq = (double)v.x * v.x + (double)v.y * v.y + (double)v.z * v.z + (double)v.w * v.w;
        #pragma unroll
        for (int off = 32; off > 0; off >>= 1) sq += __shfl_down(sq, off, 64);
        if (lane == 0) wsq[k] = (float)sq;
    } else {
        int r = (blockIdx.x - 2048) * 4 + wave;
        float4 v = reinterpret_cast<const float4*>(x)[(size_t)r * 64 + lane];
        double sq = (double)v.x * v.x + (double)v.y * v.y + (double)v.z * v.z + (double)v.w * v.w;
        float am = fmaxf(fmaxf(fabsf(v.x), fabsf(v.y)), fmaxf(fabsf(v.z), fabsf(v.w)));
        #pragma unroll
        for (int off = 32; off > 0; off >>= 1) {
            sq += __shfl_down(sq, off, 64);
            am = fmaxf(am, __shfl_down(am, off, 64));
        }
        if (lane == 0) {
            xsq[r] = (float)sq;
            am = fmaxf(am, 1e-20f);
            float s = 127.0f / am;
            sx[r] = s;
            invs[r] = 1.0f / (s * SW_F);
        }
    }
}

// Pass 1: int8 MFMA argmin (A in regs, K=32/inst), inline candidate extraction.
__global__ __launch_bounds__(256, 3) void pass1_kernel(
        const float* __restrict__ x, const char* __restrict__ wq,
        const float* __restrict__ wsq, const float* __restrict__ sx,
        const float* __restrict__ invs, float* __restrict__ idx_out,
        int* __restrict__ hard, unsigned* __restrict__ hard_count,
        int* __restrict__ candcnt, int* __restrict__ cands) {
    __shared__ __align__(16) char smem[33280];       // 32 KB staging | 33.3 KB epilogue

    const int t = threadIdx.x;
    const int lane = t & 63, ln31 = lane & 31, h = lane >> 5;
    const int wv = t >> 6, rs = wv & 1, cs = wv >> 1;
    const int r0 = blockIdx.x * 64;

    // A fragments: this wave's 32 rows, quantized to int8 with per-row Sx
    const int arow = r0 + rs * 32 + ln31;
    const float4* xr = reinterpret_cast<const float4*>(x) + (size_t)arow * 64;
    const float Sx_r = sx[arow];
    i32x4 afr[8];
    #pragma unroll
    for (int kk = 0; kk < 8; ++kk) {
        unsigned u0 = q4(xr[kk * 8 + h * 4 + 0], Sx_r);
        unsigned u1 = q4(xr[kk * 8 + h * 4 + 1], Sx_r);
        unsigned u2 = q4(xr[kk * 8 + h * 4 + 2], Sx_r);
        unsigned u3 = q4(xr[kk * 8 + h * 4 + 3], Sx_r);
        afr[kk] = (i32x4){(int)u0, (int)u1, (int)u2, (int)u3};
    }
    float invSr[16];
    #pragma unroll
    for (int r = 0; r < 16; ++r) {
        int rl = rs * 32 + (r & 3) + 8 * (r >> 2) + 4 * h;   // C/D row map (verified R5-R7)
        invSr[r] = invs[r0 + rl];
    }

    float b1[16], b2[16];
    #pragma unroll
    for (int r = 0; r < 16; ++r) { b1[r] = 3.4e38f; b2[r] = 3.4e38f; }

    const int col0 = cs * 64 + ln31, c15 = ln31 & 15;
    const char* gW = wq + (size_t)wv * 8192 + (size_t)lane * 16;
    char* lW = smem + wv * 8192;

    for (int tile = 0; tile < 64; ++tile) {
        __syncthreads();                              // previous tile fully consumed
        const char* gt = gW + (size_t)tile * 32768;
        #pragma unroll
        for (int i = 0; i < 8; ++i)
            ASYNC_COPY16(gt + i * 1024, lW + i * 1024);
        __syncthreads();                              // drains vmcnt before reads

        int kb0 = tile * 128 + col0;
        float wsk0 = wsq[kb0], wsk1 = wsq[kb0 + 32];

        i32x16 acc0 = {0,0,0,0,0,0,0,0,0,0,0,0,0,0,0,0};
        i32x16 acc1 = {0,0,0,0,0,0,0,0,0,0,0,0,0,0,0,0};
        #pragma unroll
        for (int kk = 0; kk < 8; ++kk) {
            int off = ((kk * 2 + h) ^ c15) << 4;
            i32x4 bf0 = *reinterpret_cast<const i32x4*>(smem + col0 * 256 + off);
            i32x4 bf1 = *reinterpret_cast<const i32x4*>(smem + (col0 + 32) * 256 + off);
            acc0 = __builtin_amdgcn_mfma_i32_32x32x32_i8(afr[kk], bf0, acc0, 0, 0, 0);
            acc1 = __builtin_amdgcn_mfma_i32_32x32x32_i8(afr[kk], bf1, acc1, 0, 0, 0);
        }

        #pragma unroll
        for (int r = 0; r < 16; ++r) {
            float s0 = fmaf((float)acc0[r], invSr[r], wsk0);
            float p0 = __uint_as_float((__float_as_uint(s0) & 0xFFFFE000u) | (unsigned)kb0);
            b2[r] = __builtin_amdgcn_fmed3f(p0, b1[r], b2[r]);
            b1[r] = fminf(p0, b1[r]);
            float s1 = fmaf((float)acc1[r], invSr[r], wsk1);
            float p1 = __uint_as_float((__float_as_uint(s1) & 0xFFFFE000u) | (unsigned)(kb0 + 32));
            b2[r] = __builtin_amdgcn_fmed3f(p1, b1[r], b2[r]);
            b1[r] = fminf(p1, b1[r]);
        }
    }

    // per-row slot arrays in LDS (stride 65)
    __syncthreads();
    float* sb1 = reinterpret_cast<float*>(smem);      // [64][65]
    float* sb2 = sb1 + 4160;                          // [64][65]
    #pragma unroll
    for (int r = 0; r < 16; ++r) {
        int rl = rs * 32 + (r & 3) + 8 * (r >> 2) + 4 * h;
        sb1[rl * 65 + cs * 32 + ln31] = b1[r];
        sb2[rl * 65 + cs * 32 + ln31] = b2[r];
    }
    __syncthreads();
    if (t < 64) {
        float B1 = 3.4e38f, B2 = 3.4e38f;
        for (int c = 0; c < 64; ++c) {
            float a1 = sb1[t * 65 + c], a2 = sb2[t * 65 + c];
            float nb2 = fminf(fmaxf(B1, a1), fminf(B2, a2));  // 2nd-smallest of {B1,B2,a1,a2}
            B1 = fminf(B1, a1);
            B2 = nb2;
        }
        int row = r0 + t;
        idx_out[row] = (float)(__float_as_uint(B1) & 0x1FFFu);
        int nc = 0;
        if (B2 - B1 <= M_FLAG) {
            // Lemma: dropped scores in slot L >= final b2(L). If b2(L) > T for all L,
            // {b1(L) <= T} is the complete candidate set; else row is "hard".
            float T = B1 + M_CAND;
            bool hardrow = false;
            for (int c = 0; c < 64; ++c) {
                float a1 = sb1[t * 65 + c];
                if (a1 <= T) {
                    if (nc < CAP) cands[row * CAP + nc] = (int)(__float_as_uint(a1) & 0x1FFFu);
                    ++nc;
                }
                if (sb2[t * 65 + c] <= T) hardrow = true;
            }
            if (nc > CAP) hardrow = true;
            if (hardrow) {
                nc = -1;
                *reinterpret_cast<unsigned long long*>(&cands[row * CAP]) = ~0ULL;
                unsigned hp = atomicAdd(hard_count, 1u);
                if (hp < N_ROWS) hard[hp] = row;
            }
        }
        candcnt[row] = nc;
    }
}

// fixup: np-exact full scan for the rare hard rows, packed u64 atomicMin
// (exact np fp32 sequence, lowest-k tie via key low bits)
__global__ __launch_bounds__(256) void fixup_kernel(
        const float* __restrict__ x, const float* __restrict__ w,
        const float* __restrict__ wsq, const float* __restrict__ xsq,
        const int* __restrict__ hard, const unsigned* __restrict__ hard_count,
        int* __restrict__ cands) {
    const int lane = threadIdx.x & 63, wv = threadIdx.x >> 6;
    unsigned cu = hard_count[0];
    int cnt = cu > N_ROWS ? N_ROWS : (int)cu;
    int units = cnt * 32;                      // unit = 256 codewords of one row

    for (int u = blockIdx.x; u < units; u += 512) {
        int row = hard[u >> 5];
        int seg = u & 31;
        float4 xv = reinterpret_cast<const float4*>(x)[(size_t)row * 64 + lane];
        float Xs = xsq[row];
        float bq = 3.4e38f; int bk = -1;
        for (int i = 0; i < 64; ++i) {
            int k = seg * 256 + wv * 64 + i;
            float4 wv4 = reinterpret_cast<const float4*>(w)[(size_t)k * 64 + lane];
            double d = (double)xv.x * wv4.x + (double)xv.y * wv4.y
                     + (double)xv.z * wv4.z + (double)xv.w * wv4.w;
            #pragma unroll
            for (int off = 1; off < 64; off <<= 1) d += __shfl_xor(d, off, 64);
            float XW = (float)d;
            float t3 = fmaf(-2.0f, XW, Xs);
            float qv = t3 + wsq[k];
            if (qv < bq || bk < 0) { bq = qv; bk = k; }   // k ascending: lowest-k ties kept
        }
        if (lane == 0) {
            unsigned b = __float_as_uint(bq);
            unsigned mono = (b & 0x80000000u) ? ~b : (b | 0x80000000u);
            unsigned long long key = ((unsigned long long)mono << 13) | (unsigned)bk;
            atomicMin(reinterpret_cast<unsigned long long*>(&cands[row * CAP]), key);
        }
    }
}

// gather + inline np-exact rescore + loss + last-block finalize
__global__ __launch_bounds__(256) void gather_kernel(
        const float* __restrict__ x, const float* __restrict__ w,
        const float* __restrict__ wsq, const float* __restrict__ xsq,
        const int* __restrict__ candcnt, const int* __restrict__ cands,
        float* __restrict__ idx_out, float* __restrict__ out_q,
        float* __restrict__ accum, unsigned* __restrict__ done,
        float* __restrict__ out_tail) {
    const int lane = threadIdx.x & 63, wv = threadIdx.x >> 6;
    float lsum = 0.0f;
    #pragma unroll
    for (int rr = 0; rr < 2; ++rr) {
        int row = blockIdx.x * 8 + wv * 2 + rr;
        int nc = candcnt[row];
        int k;
        float4 xv = reinterpret_cast<const float4*>(x)[(size_t)row * 64 + lane];
        if (nc == 0) {
            k = (int)idx_out[row];
        } else if (nc < 0) {
            unsigned long long key =
                *reinterpret_cast<const unsigned long long*>(&cands[row * CAP]);
            k = (int)(key & 0x1FFFULL);
        } else {
            float Xs = xsq[row];
            float bq = 3.4e38f; int bk = -1;
            for (int c = 0; c < nc; ++c) {
                int kc = cands[row * CAP + c];
                float4 wv4 = reinterpret_cast<const float4*>(w)[(size_t)kc * 64 + lane];
                double d = (double)xv.x * wv4.x + (double)xv.y * wv4.y
                         + (double)xv.z * wv4.z + (double)xv.w * wv4.w;
                #pragma unroll
                for (int off = 1; off < 64; off <<= 1) d += __shfl_xor(d, off, 64);
                float XW = (float)d;
                float t3 = fmaf(-2.0f, XW, Xs);
                float qv = t3 + wsq[kc];
                if (qv < bq || (qv == bq && kc < bk) || bk < 0) { bq = qv; bk = kc; }
            }
            k = bk;
        }
        float4 qv4 = reinterpret_cast<const float4*>(w)[(size_t)k * 64 + lane];
        float4 ov;
        ov.x = xv.x + (qv4.x - xv.x);
        ov.y = xv.y + (qv4.y - xv.y);
        ov.z = xv.z + (qv4.z - xv.z);
        ov.w = xv.w + (qv4.w - xv.w);
        reinterpret_cast<float4*>(out_q)[(size_t)row * 64 + lane] = ov;
        float dx = xv.x - qv4.x, dy = xv.y - qv4.y, dz = xv.z - qv4.z, dw = xv.w - qv4.w;
        lsum += dx * dx + dy * dy + dz * dz + dw * dw;
        if (nc != 0 && lane == 0) idx_out[row] = (float)k;
    }
    #pragma unroll
    for (int off = 32; off > 0; off >>= 1) lsum += __shfl_down(lsum, off, 64);
    __shared__ float ssum[4];
    if (lane == 0) ssum[wv] = lsum;
    __syncthreads();
    if (threadIdx.x == 0) {
        atomicAdd(accum, ssum[0] + ssum[1] + ssum[2] + ssum[3]);
        __threadfence();
        unsigned d = atomicAdd(done, 1u);
        if (d == gridDim.x - 1) {                     // last block finalizes
            __threadfence();
            float tot = atomicAdd(accum, 0.0f);       // atomic read of final sum
            float mse = tot / (float)Q_ELEMS;
            float commit = 0.25f * mse;
            out_tail[0] = commit;
            out_tail[1] = mse;
            out_tail[2] = commit + mse;
        }
    }
}

extern "C" void kernel_launch(void* const* d_in, const int* in_sizes, int n_in,
                              void* d_out, int out_size, void* d_ws, size_t ws_size,
                              hipStream_t stream) {
    const float* x = (const float*)d_in[0];
    const float* w = (const float*)d_in[1];
    float* out = (float*)d_out;

    char* ws = (char*)d_ws;
    float*    Wsq      = (float*)ws;
    float*    Xsq      = (float*)(ws + 32768);
    float*    Sx       = (float*)(ws + 163840);
    float*    invS     = (float*)(ws + 294912);
    float*    accum    = (float*)(ws + 425984);
    unsigned* counters = (unsigned*)(ws + 425984);   // accum, hard_count, done
    unsigned* hard_cnt = (unsigned*)(ws + 425988);
    unsigned* done     = (unsigned*)(ws + 425992);
    int*      hard     = (int*)(ws + 426000);
    int*      candcnt  = (int*)(ws + 557072);
    int*      cands    = (int*)(ws + 688144);
    char*     Wq       = (char*)(ws + 2785296);

    prep_kernel<<<10240, 256, 0, stream>>>(w, x, Wsq, Xsq, Sx, invS, Wq, counters);
    pass1_kernel<<<N_ROWS / 64, 256, 0, stream>>>(x, Wq, Wsq, Sx, invS, out + Q_ELEMS,
                                                  hard, hard_cnt, candcnt, cands);
    fixup_kernel<<<512, 256, 0, stream>>>(x, w, Wsq, Xsq, hard, hard_cnt, cands);
    gather_kernel<<<N_ROWS / 8, 256, 0, stream>>>(x, w, Wsq, Xsq, candcnt, cands,
                                                  out + Q_ELEMS, out, accum, done,
                                                  out + Q_ELEMS + N_ROWS);
}